// Round 5
// baseline (333.750 us; speedup 1.0000x reference)
//
#include <hip/hip_runtime.h>
#include <math.h>

#define F_OUT     32
#define GRID_DIM  32
#define NUM_VOX   (GRID_DIM * GRID_DIM * GRID_DIM)

#define NPB   64             // nodes per bucket/owner block; bucket = dst >> 6
#define NB    1024           // max buckets (Nn <= 65536)
#define CAP   2048           // slots per bucket (mean 1024, sd 32 -> +32 sigma)
#define SWS   33             // sW row stride -> bank (k+o)&31, conflict-free
#define SAS   33             // sAgg row stride -> bank (rel+o)&31, conflict-free

// ---------- monotonic float<->uint encoding for atomicMax on signed floats ----
__device__ __forceinline__ unsigned int enc_f32(float f) {
    unsigned int u = __float_as_uint(f);
    return (u & 0x80000000u) ? ~u : (u | 0x80000000u);
}
__device__ __forceinline__ float dec_f32(unsigned int e) {
    return (e & 0x80000000u) ? __uint_as_float(e ^ 0x80000000u)
                             : __uint_as_float(~e);
}

// ---------- K1: bucket edges (no sort passes; fixed-capacity reservation) ----
__global__ __launch_bounds__(256) void scatter_kernel(
    const float* __restrict__ x, const int* __restrict__ src,
    const int* __restrict__ dst, const float* __restrict__ pseudo,
    int* __restrict__ count,           // NB cursors, 64B-padded
    float4* __restrict__ payload,      // [NB * CAP]
    int E, int epb)
{
    int e = blockIdx.x * 256 + threadIdx.x;
    if (e >= E) return;
    int d = dst[e];
    int b = d >> 6;
    int slot = atomicAdd(&count[b * 16], 1);
    if (slot >= epb) return;                       // statistically unreachable
    float xj = x[src[e]];
    float p0 = pseudo[3 * e], p1 = pseudo[3 * e + 1], p2 = pseudo[3 * e + 2];
    unsigned int q2 = (unsigned int)(p2 * 65535.0f + 0.5f);   // p2 in [0,1)
    unsigned int w  = (q2 & 0xFFFFu) | ((unsigned int)(d & 63) << 16);
    payload[(size_t)b * epb + slot] = make_float4(p0, p1, xj, __uint_as_float(w));
}

// ---------- K2: owner block — direct channel accumulation + epilogue ---------
__global__ __launch_bounds__(512) void owner_kernel(
    const float4* __restrict__ payload, const int* __restrict__ count,
    const float* __restrict__ W,        // [125,32]
    const float* __restrict__ x,        // [N,1]
    const float* __restrict__ W_root,   // [32]
    const float* __restrict__ bias,     // [32]
    const float* __restrict__ pos,      // [N,3]
    unsigned int* __restrict__ pooled,  // [NUM_VOX,32] encoded
    int Nn, int epb)
{
    __shared__ float sW[125 * SWS];     // 16500 B
    __shared__ float sAgg[NPB * SAS];   //  8448 B
    __shared__ float sDeg[NPB];         //   256 B   (~25 KB total -> 4 blk/CU)

    const int tid = threadIdx.x;
    for (int i = tid; i < 125 * F_OUT; i += 512)
        sW[(i >> 5) * SWS + (i & 31)] = W[i];
    for (int i = tid; i < NPB * SAS; i += 512) sAgg[i] = 0.0f;
    if (tid < NPB) sDeg[tid] = 0.0f;
    __syncthreads();

    const int b  = blockIdx.x;
    int ne = count[b * 16]; if (ne > epb) ne = epb;
    const float4* pl = payload + (size_t)b * epb;

    const int o    = tid & 31;          // channel (lane & 31)
    const int half = (tid >> 5) & 1;    // which edge of the wave's pair
    const int wv   = tid >> 6;          // wave id 0..7

    // each wave handles 2 edges per iteration; block consumes 16/iter
    for (int e = wv * 2 + half; e < ne; e += 16) {
        float4 r = pl[e];               // broadcast within half-wave
        float xj = r.z;
        unsigned int w = __float_as_uint(r.w);
        int   rel = (int)(w >> 16);
        float p2  = (float)(w & 0xFFFFu) * (1.0f / 65535.0f);

        float v0 = r.x * 4.0f, v1 = r.y * 4.0f, v2 = p2 * 4.0f;
        float i0 = fminf(fmaxf(floorf(v0), 0.0f), 3.0f);
        float i1 = fminf(fmaxf(floorf(v1), 0.0f), 3.0f);
        float i2 = fminf(fmaxf(floorf(v2), 0.0f), 3.0f);
        float f0 = v0 - i0, f1 = v1 - i1, f2 = v2 - i2;
        float g0 = 1.0f - f0, g1 = 1.0f - f1, g2 = 1.0f - f2;
        int k = (int)i0 + 5 * (int)i1 + 25 * (int)i2;     // 0..93

        float a2 = xj * g2, b2 = xj * f2;
        float wA0 = (g0 * g1) * a2, wA1 = (f0 * g1) * a2;
        float wA2 = (g0 * f1) * a2, wA3 = (f0 * f1) * a2;
        float wB0 = (g0 * g1) * b2, wB1 = (f0 * g1) * b2;
        float wB2 = (g0 * f1) * b2, wB3 = (f0 * f1) * b2;

        const float* wp = sW + k * SWS + o;               // bank (k+o)&31
        float c = wA0 * wp[0]        + wA1 * wp[1 * SWS]
                + wA2 * wp[5 * SWS]  + wA3 * wp[6 * SWS]
                + wB0 * wp[25 * SWS] + wB1 * wp[26 * SWS]
                + wB2 * wp[30 * SWS] + wB3 * wp[31 * SWS];

        atomicAdd(&sAgg[rel * SAS + o], c);               // bank (rel+o)&31
        if (o == 0) atomicAdd(&sDeg[rel], 1.0f);
    }
    __syncthreads();

    // ---- epilogue: mean + root + bias + ELU + coalesced voxel scatter-max ----
    const int n0 = b * NPB;
    for (int item = tid; item < NPB * F_OUT; item += 512) {
        int nr = item >> 5, oo = item & 31;
        int n = n0 + nr;
        if (n >= Nn) break;
        float dg = fmaxf(sDeg[nr], 1.0f);
        float h = sAgg[nr * SAS + oo] / dg + x[n] * W_root[oo] + bias[oo];
        h = (h > 0.0f) ? h : expm1f(h);

        int vx = min(max((int)floorf(pos[3 * n + 0] * (float)GRID_DIM), 0), GRID_DIM - 1);
        int vy = min(max((int)floorf(pos[3 * n + 1] * (float)GRID_DIM), 0), GRID_DIM - 1);
        int vz = min(max((int)floorf(pos[3 * n + 2] * (float)GRID_DIM), 0), GRID_DIM - 1);
        int vidx = vx + GRID_DIM * vy + GRID_DIM * GRID_DIM * vz;
        atomicMax(&pooled[(size_t)vidx * F_OUT + oo], enc_f32(h));
    }
}

// ---------- K3: decode, empty voxels -> 0 ------------------------------------
__global__ __launch_bounds__(256) void finalize_kernel(
    const unsigned int* __restrict__ pooled,
    float* __restrict__ out, int M)
{
    int i = blockIdx.x * blockDim.x + threadIdx.x;
    if (i >= M) return;
    unsigned int u = pooled[i];
    out[i] = (u == 0u) ? 0.0f : dec_f32(u);
}

// ============================ launcher =======================================
extern "C" void kernel_launch(void* const* d_in, const int* in_sizes, int n_in,
                              void* d_out, int out_size, void* d_ws, size_t ws_size,
                              hipStream_t stream) {
    const float* x       = (const float*)d_in[0];
    const int*   ei      = (const int*)  d_in[1];
    const float* pseudo  = (const float*)d_in[2];
    const float* pos     = (const float*)d_in[3];
    const float* W       = (const float*)d_in[4];
    const float* W_root  = (const float*)d_in[5];
    const float* bias    = (const float*)d_in[6];
    float* out = (float*)d_out;

    const int E  = in_sizes[1] / 2;
    const int Nn = in_sizes[0];                 // F_IN == 1, Nn <= 65536
    const int nb = (Nn + NPB - 1) / NPB;        // buckets actually used

    // workspace: [pooled 4MB][count 64KB][payload nb*epb*16]
    const size_t pooled_b = (size_t)NUM_VOX * F_OUT * 4;
    const size_t count_b  = (size_t)NB * 16 * 4;
    unsigned int* pooled  = (unsigned int*)d_ws;
    int*          count   = (int*)((char*)d_ws + pooled_b);
    float4*       payload = (float4*)((char*)d_ws + pooled_b + count_b);

    // per-bucket capacity from available workspace, capped at CAP
    size_t avail = (ws_size > pooled_b + count_b) ? ws_size - pooled_b - count_b : 0;
    int epb = (int)(avail / ((size_t)nb * 16));
    if (epb > CAP) epb = CAP;

    hipMemsetAsync(d_ws, 0, pooled_b + count_b, stream);

    scatter_kernel<<<(E + 255) / 256, 256, 0, stream>>>(
        x, ei, ei + E, pseudo, count, payload, E, epb);

    owner_kernel<<<nb, 512, 0, stream>>>(
        payload, count, W, x, W_root, bias, pos, pooled, Nn, epb);

    const int M = (out_size < NUM_VOX * F_OUT) ? out_size : NUM_VOX * F_OUT;
    finalize_kernel<<<(M + 255) / 256, 256, 0, stream>>>(pooled, out, M);
}

// Round 6
// 173.299 us; speedup vs baseline: 1.9259x; 1.9259x over previous
//
#include <hip/hip_runtime.h>
#include <math.h>

#define F_OUT     32
#define GRID_DIM  32
#define NUM_VOX   (GRID_DIM * GRID_DIM * GRID_DIM)

#define NPB   64             // nodes per bucket; bucket = dst >> 6 (Nn <= 65536 -> <= 1024 buckets)
#define NBKT  1024           // bucket table size
#define SEB   4096           // edges per sort block
#define SCS   127            // sC row stride: (node*127+k)&31 distinct-ish -> 2-way max (free)
#define FOCAP 2048           // frag-of-edge map capacity (mean ne=1024, +32 sigma)

// ---------- monotonic float<->uint encoding for atomicMax on signed floats ----
__device__ __forceinline__ unsigned int enc_f32(float f) {
    unsigned int u = __float_as_uint(f);
    return (u & 0x80000000u) ? ~u : (u | 0x80000000u);
}
__device__ __forceinline__ float dec_f32(unsigned int e) {
    return (e & 0x80000000u) ? __uint_as_float(e ^ 0x80000000u)
                             : __uint_as_float(~e);
}

// ---------- K1: block-local counting sort by bucket, coalesced output --------
__global__ __launch_bounds__(512) void sort_kernel(
    const int*   __restrict__ src,
    const int*   __restrict__ dst,
    const float* __restrict__ x,
    const float* __restrict__ pseudo,
    float4* __restrict__ payload,          // [nSB * SEB]
    unsigned int* __restrict__ off_tab,    // [nSB][NBKT+1]
    int E)
{
    __shared__ unsigned int   sHist[NBKT];     // hist, then cursor
    __shared__ unsigned int   sStart[NBKT];    // exclusive prefix
    __shared__ unsigned int   sScan[512];
    __shared__ unsigned int   sPairE[SEB];
    __shared__ unsigned short sPairD[SEB];

    const int t   = threadIdx.x;
    const int blk = blockIdx.x;
    const int e0  = blk * SEB;

    for (int i = t; i < NBKT; i += 512) sHist[i] = 0;
    __syncthreads();

    // pass A: histogram (keep dst in regs)
    unsigned short dloc[8];
    #pragma unroll
    for (int i = 0; i < 8; ++i) {
        int e = e0 + i * 512 + t;
        if (e < E) {
            int d = dst[e];
            dloc[i] = (unsigned short)d;
            atomicAdd(&sHist[d >> 6], 1u);
        } else dloc[i] = 0;
    }
    __syncthreads();

    // exclusive scan of 1024 buckets: pair-sum -> 512-wide Hillis-Steele -> expand
    unsigned int a0 = sHist[2 * t], a1 = sHist[2 * t + 1];
    sScan[t] = a0 + a1;
    __syncthreads();
    for (int ofs = 1; ofs < 512; ofs <<= 1) {
        unsigned int v = (t >= ofs) ? sScan[t - ofs] : 0u;
        __syncthreads();
        sScan[t] += v;
        __syncthreads();
    }
    unsigned int excl = sScan[t] - (a0 + a1);
    sStart[2 * t]     = excl;
    sStart[2 * t + 1] = excl + a0;
    __syncthreads();
    sHist[2 * t]     = excl;          // reuse as cursor
    sHist[2 * t + 1] = excl + a0;
    __syncthreads();

    // pass B: place (e, d) into LDS by bucket
    #pragma unroll
    for (int i = 0; i < 8; ++i) {
        int e = e0 + i * 512 + t;
        if (e < E) {
            unsigned int slot = atomicAdd(&sHist[dloc[i] >> 6], 1u);
            sPairE[slot] = (unsigned int)e;
            sPairD[slot] = dloc[i];
        }
    }
    __syncthreads();

    int total = E - e0; if (total > SEB) total = SEB;

    // streamout: gather payload fields, write coalesced to private slab
    for (int i = t; i < total; i += 512) {
        unsigned int e = sPairE[i];
        unsigned int d = sPairD[i];
        float xj = x[src[e]];
        float p0 = pseudo[3 * e], p1 = pseudo[3 * e + 1], p2 = pseudo[3 * e + 2];
        unsigned int q2 = (unsigned int)(p2 * 65535.0f + 0.5f) & 0xFFFFu;
        unsigned int w  = q2 | ((d & 63u) << 16);
        payload[(size_t)e0 + i] = make_float4(p0, p1, xj, __uint_as_float(w));
    }

    // offset table (exact; no capacity risk)
    for (int b = t; b < NBKT; b += 512)
        off_tab[(size_t)blk * (NBKT + 1) + b] = (unsigned int)e0 + sStart[b];
    if (t == 0)
        off_tab[(size_t)blk * (NBKT + 1) + NBKT] = (unsigned int)(e0 + total);
}

// ---------- K2: owner block — LDS accumulate C, dense GEMM, epilogue ---------
__global__ __launch_bounds__(512) void owner_kernel(
    const float4* __restrict__ payload,
    const unsigned int* __restrict__ off_tab,
    const float* __restrict__ W,        // [125,32]
    const float* __restrict__ x,        // [N,1]
    const float* __restrict__ W_root,   // [32]
    const float* __restrict__ bias,     // [32]
    const float* __restrict__ pos,      // [N,3]
    unsigned int* __restrict__ pooled,  // [NUM_VOX,32] encoded
    int Nn, int nSB)
{
    __shared__ __align__(16) float sC[NPB * SCS];   // 32512 B
    __shared__ unsigned int  sGS[256];              // frag global start
    __shared__ unsigned int  sLS[257];              // frag local start (excl scan)
    __shared__ unsigned int  sTmp[256];
    __shared__ unsigned char sFO[FOCAP];            // frag id per local edge idx

    const int t = threadIdx.x;
    const int b = blockIdx.x;

    // zero sC (8128 floats = 2032 float4)
    for (int i = t; i < NPB * SCS / 4; i += 512)
        *(float4*)&sC[i * 4] = make_float4(0.f, 0.f, 0.f, 0.f);

    // fragment table: start + count per sort-block
    unsigned int cnt = 0;
    if (t < 256) {
        if (t < nSB) {
            unsigned int s  = off_tab[(size_t)t * (NBKT + 1) + b];
            unsigned int e_ = off_tab[(size_t)t * (NBKT + 1) + b + 1];
            sGS[t] = s;
            cnt = e_ - s;
        } else sGS[t] = 0;
        sTmp[t] = cnt;
    }
    __syncthreads();
    for (int ofs = 1; ofs < 256; ofs <<= 1) {
        unsigned int v = 0;
        if (t < 256 && t >= ofs) v = sTmp[t - ofs];
        __syncthreads();
        if (t < 256) sTmp[t] += v;
        __syncthreads();
    }
    if (t < 256) sLS[t] = sTmp[t] - cnt;
    if (t == 255) sLS[256] = sTmp[255];
    __syncthreads();
    const int ne = (int)sLS[256];

    // frag-of-edge map (overflow handled by binary search below)
    if (t < 256 && t < nSB) {
        unsigned int ls = sLS[t];
        for (unsigned int j = 0; j < cnt; ++j) {
            unsigned int idx = ls + j;
            if (idx < FOCAP) sFO[idx] = (unsigned char)t;
        }
    }
    __syncthreads();

    // ---- edge phase: 9 scattered LDS atomics per edge (edge-parallel) ----
    for (int i = t; i < ne; i += 512) {
        int f;
        if (i < FOCAP) f = sFO[i];
        else {                                   // statistically unreachable
            int lo = 0, hi = 255;
            while (lo < hi) {
                int mid = (lo + hi + 1) >> 1;
                if (sLS[mid] <= (unsigned int)i) lo = mid; else hi = mid - 1;
            }
            f = lo;
        }
        unsigned int g = sGS[f] + ((unsigned int)i - sLS[f]);
        float4 r = payload[g];

        float xj = r.z;
        unsigned int w = __float_as_uint(r.w);
        int   rel = (int)((w >> 16) & 63u);
        float p2  = (float)(w & 0xFFFFu) * (1.0f / 65535.0f);

        float v0 = r.x * 4.0f, v1 = r.y * 4.0f, v2 = p2 * 4.0f;
        float i0 = fminf(fmaxf(floorf(v0), 0.0f), 3.0f);
        float i1 = fminf(fmaxf(floorf(v1), 0.0f), 3.0f);
        float i2 = fminf(fmaxf(floorf(v2), 0.0f), 3.0f);
        float f0 = v0 - i0, f1 = v1 - i1, f2 = v2 - i2;
        float g0 = 1.0f - f0, g1 = 1.0f - f1, g2 = 1.0f - f2;
        int k = (int)i0 + 5 * (int)i1 + 25 * (int)i2;    // 0..93

        float w00 = g0 * g1, w10 = f0 * g1, w01 = g0 * f1, w11 = f0 * f1;
        float a2 = xj * g2, b2 = xj * f2;
        float* row = sC + rel * SCS;
        atomicAdd(row + k +  0, w00 * a2);
        atomicAdd(row + k +  1, w10 * a2);
        atomicAdd(row + k +  5, w01 * a2);
        atomicAdd(row + k +  6, w11 * a2);
        atomicAdd(row + k + 25, w00 * b2);
        atomicAdd(row + k + 26, w10 * b2);
        atomicAdd(row + k + 30, w01 * b2);
        atomicAdd(row + k + 31, w11 * b2);
        atomicAdd(row + 125, 1.0f);                      // degree
    }
    __syncthreads();

    // ---- dense GEMM: [64 x 125] @ [125 x 32], 4 channels/thread ----
    const int node = t & 63;
    const int cg   = t >> 6;                // wave-uniform channel group 0..7
    const float* crow = sC + node * SCS;
    float4 acc = make_float4(0.f, 0.f, 0.f, 0.f);
    #pragma unroll 5
    for (int k = 0; k < 125; ++k) {
        float r = crow[k];
        float4 wv = *(const float4*)(W + k * F_OUT + cg * 4);
        acc.x += r * wv.x; acc.y += r * wv.y;
        acc.z += r * wv.z; acc.w += r * wv.w;
    }
    float dg = fmaxf(crow[125], 1.0f);
    int   n  = b * NPB + node;
    float xn = (n < Nn) ? x[n] : 0.0f;
    float4 wr = *(const float4*)(W_root + cg * 4);
    float4 bs = *(const float4*)(bias + cg * 4);
    __syncthreads();                        // all sC reads done

    // ---- epilogue into sC slots 0..31 per node ----
    if (n < Nn) {
        float h;
        h = acc.x / dg + xn * wr.x + bs.x; h = h > 0.f ? h : expm1f(h); sC[node * SCS + cg * 4 + 0] = h;
        h = acc.y / dg + xn * wr.y + bs.y; h = h > 0.f ? h : expm1f(h); sC[node * SCS + cg * 4 + 1] = h;
        h = acc.z / dg + xn * wr.z + bs.z; h = h > 0.f ? h : expm1f(h); sC[node * SCS + cg * 4 + 2] = h;
        h = acc.w / dg + xn * wr.w + bs.w; h = h > 0.f ? h : expm1f(h); sC[node * SCS + cg * 4 + 3] = h;
    }
    __syncthreads();

    // ---- voxel scatter-max, channel-coalesced ----
    for (int item = t; item < NPB * F_OUT; item += 512) {
        int nr = item >> 5, o = item & 31;
        int nn = b * NPB + nr;
        if (nn >= Nn) break;
        int vx = min(max((int)floorf(pos[3 * nn + 0] * (float)GRID_DIM), 0), GRID_DIM - 1);
        int vy = min(max((int)floorf(pos[3 * nn + 1] * (float)GRID_DIM), 0), GRID_DIM - 1);
        int vz = min(max((int)floorf(pos[3 * nn + 2] * (float)GRID_DIM), 0), GRID_DIM - 1);
        int vidx = vx + GRID_DIM * vy + GRID_DIM * GRID_DIM * vz;
        atomicMax(&pooled[(size_t)vidx * F_OUT + o], enc_f32(sC[nr * SCS + o]));
    }
}

// ---------- K3: decode, empty voxels -> 0 ------------------------------------
__global__ __launch_bounds__(256) void finalize_kernel(
    const unsigned int* __restrict__ pooled,
    float* __restrict__ out, int M)
{
    int i = blockIdx.x * blockDim.x + threadIdx.x;
    if (i >= M) return;
    unsigned int u = pooled[i];
    out[i] = (u == 0u) ? 0.0f : dec_f32(u);
}

// ============================ launcher =======================================
extern "C" void kernel_launch(void* const* d_in, const int* in_sizes, int n_in,
                              void* d_out, int out_size, void* d_ws, size_t ws_size,
                              hipStream_t stream) {
    const float* x       = (const float*)d_in[0];
    const int*   ei      = (const int*)  d_in[1];
    const float* pseudo  = (const float*)d_in[2];
    const float* pos     = (const float*)d_in[3];
    const float* W       = (const float*)d_in[4];
    const float* W_root  = (const float*)d_in[5];
    const float* bias    = (const float*)d_in[6];
    float* out = (float*)d_out;

    const int E   = in_sizes[1] / 2;
    const int Nn  = in_sizes[0];                  // F_IN == 1, Nn <= 65536
    const int nSB = (E + SEB - 1) / SEB;          // sort blocks (256 here)
    const int nb  = (Nn + NPB - 1) / NPB;         // owner buckets (1024 here)

    // workspace: [pooled 4MB][off_tab nSB*(NBKT+1)*4][payload nSB*SEB*16]
    const size_t pooled_b = (size_t)NUM_VOX * F_OUT * 4;
    const size_t off_b    = (size_t)nSB * (NBKT + 1) * 4;
    unsigned int* pooled  = (unsigned int*)d_ws;
    unsigned int* off_tab = (unsigned int*)((char*)d_ws + pooled_b);
    float4*       payload = (float4*)((char*)d_ws + pooled_b + ((off_b + 15) & ~(size_t)15));

    hipMemsetAsync(pooled, 0, pooled_b, stream);

    sort_kernel<<<nSB, 512, 0, stream>>>(ei, ei + E, x, pseudo, payload, off_tab, E);
    owner_kernel<<<nb, 512, 0, stream>>>(payload, off_tab, W, x, W_root, bias, pos,
                                         pooled, Nn, nSB);

    const int M = (out_size < NUM_VOX * F_OUT) ? out_size : NUM_VOX * F_OUT;
    finalize_kernel<<<(M + 255) / 256, 256, 0, stream>>>(pooled, out, M);
}

// Round 8
// 167.338 us; speedup vs baseline: 1.9945x; 1.0356x over previous
//
#include <hip/hip_runtime.h>
#include <math.h>

#define F_OUT     32
#define GRID_DIM  32
#define NUM_VOX   (GRID_DIM * GRID_DIM * GRID_DIM)

#define NPB   64             // nodes per bucket; bucket = dst >> 6
#define NBKT  1024           // bucket table size (Nn <= 65536)
#define SEB   2048           // edges per sort block
#define SCS   132            // sC row stride (floats): 528 B, 16B-aligned
#define DEGS  125            // degree slot within sC row
#define ECAP  3072           // owner work-list capacity (mean 1024, +64 sigma)

// ---------- monotonic float<->uint encoding for atomicMax on signed floats ----
__device__ __forceinline__ unsigned int enc_f32(float f) {
    unsigned int u = __float_as_uint(f);
    return (u & 0x80000000u) ? ~u : (u | 0x80000000u);
}
__device__ __forceinline__ float dec_f32(unsigned int e) {
    return (e & 0x80000000u) ? __uint_as_float(e ^ 0x80000000u)
                             : __uint_as_float(~e);
}

// ---------- K1: block-local counting sort, payload built in registers --------
__global__ __launch_bounds__(512) void sort_kernel(
    const int*   __restrict__ src,
    const int*   __restrict__ dst,
    const float* __restrict__ x,
    const float* __restrict__ pseudo,
    float4* __restrict__ payload,          // [nSB * SEB]
    unsigned int* __restrict__ off_tab,    // [nSB][NBKT] packed: local_start | cnt<<16
    int E)
{
    __shared__ unsigned int sHist[NBKT];   // hist -> cursor (4 KB)
    __shared__ unsigned int sStart[NBKT];  // exclusive starts (4 KB)
    __shared__ unsigned int sScan[512];    // pair-sum scan    (2 KB)
    __shared__ __align__(16) float4 sPay[SEB];   // staged payload (32 KB)

    const int t  = threadIdx.x;
    const int e0 = blockIdx.x * SEB;

    for (int i = t; i < NBKT; i += 512) sHist[i] = 0;
    __syncthreads();

    // pass A: coalesced loads, payload in registers, histogram.
    // validity is the INDEX RANGE (e < E) — no in-band sentinel: dst==65535 is legal.
    unsigned short dloc[4];
    float4 pay[4];
    #pragma unroll
    for (int i = 0; i < 4; ++i) {
        int e = e0 + i * 512 + t;
        if (e < E) {
            int d = dst[e];
            int s = src[e];
            float p0 = pseudo[3 * e], p1 = pseudo[3 * e + 1], p2 = pseudo[3 * e + 2];
            float xj = x[s];
            unsigned int q2 = (unsigned int)(p2 * 65535.0f + 0.5f) & 0xFFFFu;
            unsigned int w  = q2 | ((unsigned int)(d & 63) << 16);
            dloc[i] = (unsigned short)d;
            pay[i]  = make_float4(p0, p1, xj, __uint_as_float(w));
            atomicAdd(&sHist[d >> 6], 1u);
        } else dloc[i] = 0;
    }
    __syncthreads();

    // exclusive scan of 1024 buckets (pair-sum + 512-wide Hillis-Steele)
    unsigned int a0 = sHist[2 * t], a1 = sHist[2 * t + 1];
    sScan[t] = a0 + a1;
    __syncthreads();
    for (int ofs = 1; ofs < 512; ofs <<= 1) {
        unsigned int v = (t >= ofs) ? sScan[t - ofs] : 0u;
        __syncthreads();
        sScan[t] += v;
        __syncthreads();
    }
    unsigned int excl = sScan[t] - (a0 + a1);
    sStart[2 * t]     = excl;
    sStart[2 * t + 1] = excl + a0;
    __syncthreads();
    sHist[2 * t]     = excl;               // cursor copy
    sHist[2 * t + 1] = excl + a0;
    __syncthreads();
    const unsigned int total = sScan[511];

    // pass B: place payloads into LDS by bucket (same validity rule as pass A)
    #pragma unroll
    for (int i = 0; i < 4; ++i) {
        int e = e0 + i * 512 + t;
        if (e < E) {
            unsigned int slot = atomicAdd(&sHist[dloc[i] >> 6], 1u);
            sPay[slot] = pay[i];
        }
    }
    __syncthreads();

    // streamout: coalesced 16B stores to this block's private slab
    for (unsigned int i = t; i < total; i += 512)
        payload[(size_t)e0 + i] = sPay[i];

    // packed offset table, coalesced row write
    for (int b = t; b < NBKT; b += 512) {
        unsigned int s = sStart[b];
        unsigned int nxt = (b < NBKT - 1) ? sStart[b + 1] : total;
        off_tab[(size_t)blockIdx.x * NBKT + b] = s | ((nxt - s) << 16);
    }
}

// ---------- per-edge accumulation: 9 scattered LDS atomics -------------------
__device__ __forceinline__ void process_edge(float4 r, float* sC)
{
    float xj = r.z;
    unsigned int w = __float_as_uint(r.w);
    int   rel = (int)((w >> 16) & 63u);
    float p2  = (float)(w & 0xFFFFu) * (1.0f / 65535.0f);

    float v0 = r.x * 4.0f, v1 = r.y * 4.0f, v2 = p2 * 4.0f;
    float i0 = fminf(fmaxf(floorf(v0), 0.0f), 3.0f);
    float i1 = fminf(fmaxf(floorf(v1), 0.0f), 3.0f);
    float i2 = fminf(fmaxf(floorf(v2), 0.0f), 3.0f);
    float f0 = v0 - i0, f1 = v1 - i1, f2 = v2 - i2;
    float g0 = 1.0f - f0, g1 = 1.0f - f1, g2 = 1.0f - f2;
    int k = (int)i0 + 5 * (int)i1 + 25 * (int)i2;        // 0..93

    float w00 = g0 * g1, w10 = f0 * g1, w01 = g0 * f1, w11 = f0 * f1;
    float a2 = xj * g2, b2 = xj * f2;
    float* row = sC + rel * SCS;
    atomicAdd(row + k +  0, w00 * a2);
    atomicAdd(row + k +  1, w10 * a2);
    atomicAdd(row + k +  5, w01 * a2);
    atomicAdd(row + k +  6, w11 * a2);
    atomicAdd(row + k + 25, w00 * b2);
    atomicAdd(row + k + 26, w10 * b2);
    atomicAdd(row + k + 30, w01 * b2);
    atomicAdd(row + k + 31, w11 * b2);
    atomicAdd(row + DEGS, 1.0f);                         // degree
}

// ---------- K2: owner block — work list, LDS accumulate, GEMM, epilogue ------
__global__ __launch_bounds__(512) void owner_kernel(
    const float4* __restrict__ payload,
    const unsigned int* __restrict__ off_tab,   // [nSB][NBKT] packed
    const float* __restrict__ W,        // [125,32]
    const float* __restrict__ x,        // [N,1]
    const float* __restrict__ W_root,   // [32]
    const float* __restrict__ bias,     // [32]
    const float* __restrict__ pos,      // [N,3]
    unsigned int* __restrict__ pooled,  // [NUM_VOX,32] encoded
    int Nn, int nSB)
{
    __shared__ __align__(16) float sC[NPB * SCS];   // 33792 B
    __shared__ unsigned int sEdge[ECAP];            // 12288 B
    __shared__ unsigned int sNe;

    const int t = threadIdx.x;
    const int b = blockIdx.x;
    const int lane = t & 63;

    // zero sC
    for (int i = t; i < NPB * SCS / 4; i += 512)
        *(float4*)&sC[i * 4] = make_float4(0.f, 0.f, 0.f, 0.f);
    if (t == 0) sNe = 0;

    // my fragment (sort block t's slice of bucket b)
    unsigned int cnt = 0, start_g = 0;
    if (t < nSB) {
        unsigned int packed = off_tab[(size_t)t * NBKT + b];
        start_g = (unsigned int)t * SEB + (packed & 0xFFFFu);
        cnt = packed >> 16;
    }
    __syncthreads();

    // wave-level exclusive prefix of cnt -> compact work list offsets
    unsigned int incl = cnt;
    #pragma unroll
    for (int d = 1; d < 64; d <<= 1) {
        unsigned int v = __shfl_up(incl, d, 64);
        if (lane >= d) incl += v;
    }
    unsigned int wtot = __shfl(incl, 63, 64);
    unsigned int wbase = 0;
    if (lane == 63 && wtot > 0) wbase = atomicAdd(&sNe, wtot);
    wbase = __shfl(wbase, 63, 64);
    unsigned int off = wbase + incl - cnt;

    for (unsigned int j = 0; j < cnt; ++j) {
        unsigned int p = off + j;
        if (p < ECAP) sEdge[p] = start_g + j;
        else process_edge(payload[start_g + j], sC);   // statistically unreachable
    }
    __syncthreads();

    // edge phase: compact, divergence-free
    int ne = (int)sNe; if (ne > ECAP) ne = ECAP;
    for (int i = t; i < ne; i += 512)
        process_edge(payload[sEdge[i]], sC);
    __syncthreads();

    // dense GEMM: [64 x 125] @ [125 x 32], 4 channels/thread, b128 LDS reads
    const int node = t & 63;
    const int cg   = t >> 6;                 // wave-uniform channel group 0..7
    const float* crow = sC + node * SCS;
    float4 acc = make_float4(0.f, 0.f, 0.f, 0.f);
    #pragma unroll 8
    for (int k4 = 0; k4 < 31; ++k4) {        // k = 0..123
        float4 r = *(const float4*)&crow[k4 * 4];
        const float* wp = W + (k4 * 4) * F_OUT + cg * 4;
        float4 w0 = *(const float4*)(wp);
        float4 w1 = *(const float4*)(wp + F_OUT);
        float4 w2 = *(const float4*)(wp + 2 * F_OUT);
        float4 w3 = *(const float4*)(wp + 3 * F_OUT);
        acc.x += r.x * w0.x + r.y * w1.x + r.z * w2.x + r.w * w3.x;
        acc.y += r.x * w0.y + r.y * w1.y + r.z * w2.y + r.w * w3.y;
        acc.z += r.x * w0.z + r.y * w1.z + r.z * w2.z + r.w * w3.z;
        acc.w += r.x * w0.w + r.y * w1.w + r.z * w2.w + r.w * w3.w;
    }
    {   // k = 124
        float r = crow[124];
        const float* wp = W + 124 * F_OUT + cg * 4;
        acc.x += r * wp[0]; acc.y += r * wp[1];
        acc.z += r * wp[2]; acc.w += r * wp[3];
    }
    float dg = fmaxf(crow[DEGS], 1.0f);
    int   n  = b * NPB + node;
    float xn = (n < Nn) ? x[n] : 0.0f;
    float4 wr = *(const float4*)(W_root + cg * 4);
    float4 bs = *(const float4*)(bias + cg * 4);
    __syncthreads();                          // all sC reads done

    // epilogue into sC slots 0..31 per node
    if (n < Nn) {
        float h;
        h = acc.x / dg + xn * wr.x + bs.x; h = h > 0.f ? h : expm1f(h); sC[node * SCS + cg * 4 + 0] = h;
        h = acc.y / dg + xn * wr.y + bs.y; h = h > 0.f ? h : expm1f(h); sC[node * SCS + cg * 4 + 1] = h;
        h = acc.z / dg + xn * wr.z + bs.z; h = h > 0.f ? h : expm1f(h); sC[node * SCS + cg * 4 + 2] = h;
        h = acc.w / dg + xn * wr.w + bs.w; h = h > 0.f ? h : expm1f(h); sC[node * SCS + cg * 4 + 3] = h;
    }
    __syncthreads();

    // voxel scatter-max, channel-coalesced
    for (int item = t; item < NPB * F_OUT; item += 512) {
        int nr = item >> 5, o = item & 31;
        int nn = b * NPB + nr;
        if (nn >= Nn) break;
        int vx = min(max((int)floorf(pos[3 * nn + 0] * (float)GRID_DIM), 0), GRID_DIM - 1);
        int vy = min(max((int)floorf(pos[3 * nn + 1] * (float)GRID_DIM), 0), GRID_DIM - 1);
        int vz = min(max((int)floorf(pos[3 * nn + 2] * (float)GRID_DIM), 0), GRID_DIM - 1);
        int vidx = vx + GRID_DIM * vy + GRID_DIM * GRID_DIM * vz;
        atomicMax(&pooled[(size_t)vidx * F_OUT + o], enc_f32(sC[nr * SCS + o]));
    }
}

// ---------- K3: decode, empty voxels -> 0 ------------------------------------
__global__ __launch_bounds__(256) void finalize_kernel(
    const unsigned int* __restrict__ pooled,
    float* __restrict__ out, int M)
{
    int i = blockIdx.x * blockDim.x + threadIdx.x;
    if (i >= M) return;
    unsigned int u = pooled[i];
    out[i] = (u == 0u) ? 0.0f : dec_f32(u);
}

// ============================ launcher =======================================
extern "C" void kernel_launch(void* const* d_in, const int* in_sizes, int n_in,
                              void* d_out, int out_size, void* d_ws, size_t ws_size,
                              hipStream_t stream) {
    const float* x       = (const float*)d_in[0];
    const int*   ei      = (const int*)  d_in[1];
    const float* pseudo  = (const float*)d_in[2];
    const float* pos     = (const float*)d_in[3];
    const float* W       = (const float*)d_in[4];
    const float* W_root  = (const float*)d_in[5];
    const float* bias    = (const float*)d_in[6];
    float* out = (float*)d_out;

    const int E   = in_sizes[1] / 2;
    const int Nn  = in_sizes[0];                  // F_IN == 1, Nn <= 65536
    const int nSB = (E + SEB - 1) / SEB;          // sort blocks (512 here)
    const int nb  = (Nn + NPB - 1) / NPB;         // owner buckets (1024 here)

    // workspace: [pooled 4MB][off_tab nSB*NBKT*4][payload nSB*SEB*16]
    const size_t pooled_b = (size_t)NUM_VOX * F_OUT * 4;
    const size_t off_b    = (size_t)nSB * NBKT * 4;
    unsigned int* pooled  = (unsigned int*)d_ws;
    unsigned int* off_tab = (unsigned int*)((char*)d_ws + pooled_b);
    float4*       payload = (float4*)((char*)d_ws + pooled_b + ((off_b + 15) & ~(size_t)15));

    hipMemsetAsync(pooled, 0, pooled_b, stream);

    sort_kernel<<<nSB, 512, 0, stream>>>(ei, ei + E, x, pseudo, payload, off_tab, E);
    owner_kernel<<<nb, 512, 0, stream>>>(payload, off_tab, W, x, W_root, bias, pos,
                                         pooled, Nn, nSB);

    const int M = (out_size < NUM_VOX * F_OUT) ? out_size : NUM_VOX * F_OUT;
    finalize_kernel<<<(M + 255) / 256, 256, 0, stream>>>(pooled, out, M);
}